// Round 12
// baseline (398.751 us; speedup 1.0000x reference)
//
#include <hip/hip_runtime.h>
#include <hip/hip_bf16.h>
#include <stdint.h>

#define N_NODES 100000
#define N_EDGES 1600000
#define FEAT 128
#define EMB 128
#define N_ROOTS 4096

#define BUCKET_BITS 9
#define BUCKET_NODES 512
#define NBUCK ((N_NODES + BUCKET_NODES - 1) / BUCKET_NODES)  // 196
#define BUCK_CAP 12288
#define BIN_CHUNK 4096
#define NB_BIN ((N_EDGES + BIN_CHUNK - 1) / BIN_CHUNK)       // 391
#define BUCK_SLACK 4096
#define SRCS_CAP (N_EDGES + NBUCK * BUCK_SLACK + 4096)

typedef __attribute__((ext_vector_type(4))) float f32x4;
typedef __attribute__((ext_vector_type(8))) short bf16x8;

__device__ __forceinline__ ushort f2b(float f) {
  uint32_t u = __float_as_uint(f);
  uint32_t r = (u + 0x7FFFu + ((u >> 16) & 1u)) >> 16;  // RNE
  return (ushort)r;
}

__global__ void k_cvt_bf16(const float* __restrict__ in, ushort* __restrict__ out, int n4) {
  int i = blockIdx.x * blockDim.x + threadIdx.x;
  int stride = gridDim.x * blockDim.x;
  for (; i < n4; i += stride) {
    float4 v = ((const float4*)in)[i];
    ushort4 o;
    o.x = f2b(v.x); o.y = f2b(v.y); o.z = f2b(v.z); o.w = f2b(v.w);
    ((ushort4*)out)[i] = o;
  }
}

// W (f32 [K][128]) -> bf16 pre-swizzled to GEMM LDS layout: byte = c*2K + ((2k)^((c&7)<<4))
__global__ void k_cvtW(const float* __restrict__ W, ushort* __restrict__ Wswz, int K) {
  int idx = blockIdx.x * blockDim.x + threadIdx.x;
  if (idx >= K * 128) return;
  int k = idx >> 7, c = idx & 127;
  ushort b = f2b(W[idx]);
  *(ushort*)((char*)Wswz + c * (K * 2) + ((k * 2) ^ ((c & 7) << 4))) = b;
}

// ---- bucketed CSR build (R11) ----
__global__ __launch_bounds__(256) void k_bin(const int* __restrict__ srcA, const int* __restrict__ dstA,
                                             int* __restrict__ bucket_cnt, int* __restrict__ binned) {
  __shared__ int hist[NBUCK];
  __shared__ int lscan[NBUCK];
  __shared__ int rsv[NBUCK];
  __shared__ int lpos[NBUCK];
  __shared__ int ws[4];
  __shared__ int2 ent[BIN_CHUNK];
  int t = threadIdx.x;
  int e0 = blockIdx.x * BIN_CHUNK;
  int cnt = min(BIN_CHUNK, N_EDGES - e0);
  for (int i = t; i < NBUCK; i += 256) hist[i] = 0;
  __syncthreads();
  for (int j = t; j < cnt; j += 256) atomicAdd(&hist[dstA[e0 + j] >> BUCKET_BITS], 1);
  __syncthreads();
  {
    int lane = t & 63, wv = t >> 6;
    int v = (t < NBUCK) ? hist[t] : 0;
    int inc = v;
    for (int d = 1; d < 64; d <<= 1) { int x = __shfl_up(inc, d); if (lane >= d) inc += x; }
    if (lane == 63) ws[wv] = inc;
    __syncthreads();
    int wbase = 0;
    for (int k = 0; k < wv; ++k) wbase += ws[k];
    if (t < NBUCK) {
      int excl = wbase + inc - v;
      lscan[t] = excl;
      lpos[t] = excl;
      rsv[t] = (v > 0) ? atomicAdd(&bucket_cnt[t], v) : 0;
    }
  }
  __syncthreads();
  for (int j = t; j < cnt; j += 256) {
    int s = srcA[e0 + j], d = dstA[e0 + j];
    int p = atomicAdd(&lpos[d >> BUCKET_BITS], 1);
    ent[p] = make_int2(s, d);
  }
  __syncthreads();
  for (int j = t; j < cnt; j += 256) {
    int2 E = ent[j];
    int b = E.y >> BUCKET_BITS;
    int pos = rsv[b] + (j - lscan[b]);
    if (pos < BUCK_CAP)
      binned[b * BUCK_CAP + pos] = (E.x << BUCKET_BITS) | (E.y & (BUCKET_NODES - 1));
  }
}

__global__ __launch_bounds__(256) void k_bucket_scan(const int* __restrict__ bucket_cnt,
                                                     int* __restrict__ bucket_base) {
  __shared__ int ws[4];
  int t = threadIdx.x;
  int lane = t & 63, wv = t >> 6;
  int v = (t < NBUCK) ? bucket_cnt[t] : 0;
  int inc = v;
  for (int d = 1; d < 64; d <<= 1) { int x = __shfl_up(inc, d); if (lane >= d) inc += x; }
  if (lane == 63) ws[wv] = inc;
  __syncthreads();
  int wbase = 0;
  for (int k = 0; k < wv; ++k) wbase += ws[k];
  if (t < NBUCK) bucket_base[t] = (wbase + inc - v) + t * BUCK_SLACK;
}

__global__ __launch_bounds__(512) void k_csr(const int* __restrict__ binned,
                                             const int* __restrict__ bucket_cnt,
                                             const int* __restrict__ bucket_base,
                                             int2* __restrict__ off2, int* __restrict__ srcs) {
  __shared__ int deg[BUCKET_NODES];
  __shared__ int sAb[BUCKET_NODES];
  __shared__ int sBb[BUCKET_NODES];
  __shared__ int pos[BUCKET_NODES];
  __shared__ int epk[BUCK_CAP];
  int b = blockIdx.x;
  int t = threadIdx.x;
  int cnt = min(bucket_cnt[b], BUCK_CAP);
  int gbase = bucket_base[b];
  int n0 = b * BUCKET_NODES;
  int nn = min(BUCKET_NODES, N_NODES - n0);
  deg[t] = 0;
  __syncthreads();
  for (int j = t; j < cnt; j += 512) {
    int p = binned[b * BUCK_CAP + j];
    epk[j] = p;
    atomicAdd(&deg[p & (BUCKET_NODES - 1)], 1);
  }
  __syncthreads();
  int d = deg[t];
  int dp = (d + 7) & ~7;
  int* sA = sAb; int* sB = sBb;
  sA[t] = dp;
  __syncthreads();
  for (int q = 1; q < 512; q <<= 1) {
    int x = sA[t];
    if (t >= q) x += sA[t - q];
    sB[t] = x;
    __syncthreads();
    int* tp = sA; sA = sB; sB = tp;
  }
  int ex = sA[t] - dp;
  pos[t] = ex;
  if (t < nn) off2[n0 + t] = make_int2(gbase + ex, gbase + ex + dp);
  __syncthreads();
  for (int j = t; j < cnt; j += 512) {
    int p = epk[j];
    int q = atomicAdd(&pos[p & (BUCKET_NODES - 1)], 1);
    srcs[gbase + q] = p >> BUCKET_BITS;
  }
  __syncthreads();
  for (int q = ex + d; q < ex + dp; ++q) srcs[gbase + q] = N_NODES;  // zero-row dummies
}

// segment-sum over a bf16 node table (optional relu on gathered words) -> bf16 agg table.
// 1 wave/node, 2 cols/lane, unroll-16 two-phase. No bias/residual (moved to GEMM).
__global__ __launch_bounds__(256) void k_aggr(
    const ushort* __restrict__ table, const int2* __restrict__ off2, const int* __restrict__ srcs,
    ushort* __restrict__ outagg, int n, int relu)
{
  int node = blockIdx.x * 4 + (threadIdx.x >> 6);
  if (node >= n) return;
  int lane = threadIdx.x & 63;
  int2 se = off2[node];
  int s = __builtin_amdgcn_readfirstlane(se.x);
  int e = __builtin_amdgcn_readfirstlane(se.y);
  float a0 = 0.f, a1 = 0.f;
  int j = s;
  for (; j + 16 <= e; j += 16) {
    int ix[16];
#pragma unroll
    for (int q = 0; q < 16; ++q) ix[q] = srcs[j + q];
    uint32_t u[16];
#pragma unroll
    for (int q = 0; q < 16; ++q)
      u[q] = *(const uint32_t*)(table + (size_t)ix[q] * 128 + lane * 2);
#pragma unroll
    for (int q = 0; q < 16; ++q) {
      if (relu) { uint32_t m = (u[q] >> 15) & 0x00010001u; u[q] &= ~(m * 0xFFFFu); }
      a0 += __uint_as_float(u[q] << 16);
      a1 += __uint_as_float(u[q] & 0xFFFF0000u);
    }
  }
  if (j < e) {  // remainder exactly 8
    int ix[8];
#pragma unroll
    for (int q = 0; q < 8; ++q) ix[q] = srcs[j + q];
    uint32_t u[8];
#pragma unroll
    for (int q = 0; q < 8; ++q)
      u[q] = *(const uint32_t*)(table + (size_t)ix[q] * 128 + lane * 2);
#pragma unroll
    for (int q = 0; q < 8; ++q) {
      if (relu) { uint32_t m = (u[q] >> 15) & 0x00010001u; u[q] &= ~(m * 0xFFFFu); }
      a0 += __uint_as_float(u[q] << 16);
      a1 += __uint_as_float(u[q] & 0xFFFF0000u);
    }
  }
  uint32_t pk = (uint32_t)f2b(a0) | ((uint32_t)f2b(a1) << 16);
  *(uint32_t*)(outagg + (size_t)node * 128 + lane * 2) = pk;
}

// GEMM: out = A @ W + bias (+ resid); A = A0|A1 split at k=128; W pre-swizzled bf16 in LDS.
// outb (bf16) or outf (f32) selected by pointer.
__global__ __launch_bounds__(256) void k_gemm(
    const ushort* __restrict__ A0, const ushort* __restrict__ A1,
    const ushort* __restrict__ Wswz, const ushort* __restrict__ resid,
    const float* __restrict__ bias,
    ushort* __restrict__ outb, float* __restrict__ outf, int n, int K)
{
  extern __shared__ char smem[];
  int bytes = K * 256;
  for (int idx = threadIdx.x * 16; idx < bytes; idx += 256 * 16)
    *(uint4*)(smem + idx) = *(const uint4*)((const char*)Wswz + idx);
  __syncthreads();

  int lane = threadIdx.x & 63;
  int wv = threadIdx.x >> 6;
  int rowBase = blockIdx.x * 128 + wv * 32;
  int rl = lane & 15;
  int kh = lane >> 4;
  int r0 = rowBase + rl, r1 = r0 + 16;
  int r0c = min(r0, n - 1), r1c = min(r1, n - 1);

  f32x4 acc[2][8];
#pragma unroll
  for (int i = 0; i < 2; ++i)
#pragma unroll
    for (int j = 0; j < 8; ++j)
      acc[i][j] = (f32x4){0.f, 0.f, 0.f, 0.f};

  int nks = K >> 5;
  bf16x8 a0, a1;
  {
    int kof = (kh << 3);
    a0 = *(const bf16x8*)(A0 + (size_t)r0c * 128 + kof);
    a1 = *(const bf16x8*)(A0 + (size_t)r1c * 128 + kof);
  }
  for (int ks = 0; ks < nks; ++ks) {
    bf16x8 na0 = a0, na1 = a1;
    if (ks + 1 < nks) {
      int ksn = ks + 1;
      const ushort* Asrc = (ksn < 4) ? A0 : A1;
      int kof = ((ksn & 3) << 5) + (kh << 3);
      na0 = *(const bf16x8*)(Asrc + (size_t)r0c * 128 + kof);
      na1 = *(const bf16x8*)(Asrc + (size_t)r1c * 128 + kof);
    }
    int kk = (ks << 5) + (kh << 3);
#pragma unroll
    for (int ct = 0; ct < 8; ++ct) {
      int col = (ct << 4) + rl;
      bf16x8 b = *(const bf16x8*)(smem + col * (K * 2) + ((kk * 2) ^ ((col & 7) << 4)));
      acc[0][ct] = __builtin_amdgcn_mfma_f32_16x16x32_bf16(a0, b, acc[0][ct], 0, 0, 0);
      acc[1][ct] = __builtin_amdgcn_mfma_f32_16x16x32_bf16(a1, b, acc[1][ct], 0, 0, 0);
    }
    a0 = na0; a1 = na1;
  }
  float bv[8];
#pragma unroll
  for (int ct = 0; ct < 8; ++ct) bv[ct] = bias[(ct << 4) + rl];
#pragma unroll
  for (int ri = 0; ri < 2; ++ri)
#pragma unroll
    for (int ct = 0; ct < 8; ++ct) {
      int col = (ct << 4) + rl;
#pragma unroll
      for (int j = 0; j < 4; ++j) {
        int row = rowBase + ri * 16 + kh * 4 + j;
        if (row < n) {
          float v = acc[ri][ct][j] + bv[ct];
          if (resid) {
            ushort rr = resid[(size_t)row * 128 + col];
            v += __uint_as_float(((uint32_t)rr) << 16);
          }
          if (outf) outf[(size_t)row * 128 + col] = v;
          else outb[(size_t)row * 128 + col] = f2b(v);
        }
      }
    }
}

extern "C" void kernel_launch(void* const* d_in, const int* in_sizes, int n_in,
                              void* d_out, int out_size, void* d_ws, size_t ws_size,
                              hipStream_t stream) {
  const float* x = (const float*)d_in[0];
  const int* ei  = (const int*)d_in[1];
  const int* src = ei;
  const int* dst = ei + N_EDGES;
  const float* Wp[4] = {(const float*)d_in[4], (const float*)d_in[6],
                        (const float*)d_in[8], (const float*)d_in[10]};
  const float* bp[4] = {(const float*)d_in[5], (const float*)d_in[7],
                        (const float*)d_in[9], (const float*)d_in[11]};
  const int Kl[4] = {128, 256, 256, 256};

  char* w = (char*)d_ws;
  auto alloc = [&](size_t bytes) {
    char* p = w;
    w += (bytes + 255) & ~(size_t)255;
    return p;
  };
  ushort* x_bf  = (ushort*)alloc((size_t)(N_NODES + 8) * 128 * 2);  // + zero row
  ushort* hbf   = (ushort*)alloc((size_t)(N_NODES + 8) * 128 * 2);  // + zero row
  ushort* xagg  = (ushort*)alloc((size_t)N_NODES * 128 * 2);
  ushort* ragg  = (ushort*)alloc((size_t)N_NODES * 128 * 2);
  int2*   off2  = (int2*)  alloc((size_t)N_NODES * 8);
  int*    srcs  = (int*)   alloc((size_t)SRCS_CAP * 4);
  int*    binned = (int*)  alloc((size_t)NBUCK * BUCK_CAP * 4);
  int*    bucket_cnt  = (int*)alloc((size_t)NBUCK * 4);
  int*    bucket_base = (int*)alloc((size_t)NBUCK * 4);
  ushort* Wswz[4];
  for (int l = 0; l < 4; ++l) Wswz[l] = (ushort*)alloc((size_t)Kl[l] * 128 * 2);
  if ((size_t)(w - (char*)d_ws) > ws_size) return;

  hipMemsetAsync(bucket_cnt, 0, (size_t)NBUCK * 4, stream);
  hipMemsetAsync(x_bf + (size_t)N_NODES * 128, 0, 256, stream);  // zero rows for dummies
  hipMemsetAsync(hbf + (size_t)N_NODES * 128, 0, 256, stream);
  k_cvt_bf16<<<2048, 256, 0, stream>>>(x, x_bf, N_NODES * 128 / 4);
  for (int l = 0; l < 4; ++l)
    k_cvtW<<<(Kl[l] * 128 + 255) / 256, 256, 0, stream>>>(Wp[l], Wswz[l], Kl[l]);
  k_bin<<<NB_BIN, 256, 0, stream>>>(src, dst, bucket_cnt, binned);
  k_bucket_scan<<<1, 256, 0, stream>>>(bucket_cnt, bucket_base);
  k_csr<<<NBUCK, 512, 0, stream>>>(binned, bucket_cnt, bucket_base, off2, srcs);

  int gfull = (N_NODES + 127) / 128;
  int groot = (N_ROOTS + 127) / 128;
  int afull = (N_NODES + 3) / 4;
  int aroot = (N_ROOTS + 3) / 4;

  // xagg = segment_sum(x)  (reused by all layers; replaces layer-0's gather by linearity)
  k_aggr<<<afull, 256, 0, stream>>>(x_bf, off2, srcs, xagg, N_NODES, 0);
  // h0 = xagg @ W0 + b0
  k_gemm<<<gfull, 256, 128 * 128 * 2, stream>>>(xagg, xagg, Wswz[0], nullptr, bp[0],
                                                hbf, nullptr, N_NODES, 128);
  // layers 1-2: ragg = segment_sum(relu(h)); h += [ragg,xagg]@W + b
  for (int l = 1; l < 3; ++l) {
    k_aggr<<<afull, 256, 0, stream>>>(hbf, off2, srcs, ragg, N_NODES, 1);
    k_gemm<<<gfull, 256, 256 * 128 * 2, stream>>>(ragg, xagg, Wswz[l], hbf, bp[l],
                                                  hbf, nullptr, N_NODES, 256);
  }
  // layer 3: only roots (nodes 0..4095) are read by the output
  k_aggr<<<aroot, 256, 0, stream>>>(hbf, off2, srcs, ragg, N_ROOTS, 1);
  k_gemm<<<groot, 256, 256 * 128 * 2, stream>>>(ragg, xagg, Wswz[3], hbf, bp[3],
                                                nullptr, (float*)d_out, N_ROOTS, 256);
}

// Round 13
// 361.379 us; speedup vs baseline: 1.1034x; 1.1034x over previous
//
#include <hip/hip_runtime.h>
#include <hip/hip_bf16.h>
#include <stdint.h>

#define N_NODES 100000
#define N_EDGES 1600000
#define FEAT 128
#define EMB 128
#define N_ROOTS 4096

#define BUCKET_BITS 9
#define BUCKET_NODES 512
#define NBUCK ((N_NODES + BUCKET_NODES - 1) / BUCKET_NODES)  // 196
#define BUCK_CAP 12288
#define BIN_CHUNK 4096
#define NB_BIN ((N_EDGES + BIN_CHUNK - 1) / BIN_CHUNK)       // 391
#define BUCK_SLACK 4096
#define SRCS_CAP (N_EDGES + NBUCK * BUCK_SLACK + 4096)

#define EPI_STRIDE 132                       // f32 row stride in LDS (pad 128+4)
#define EPI_LDS (128 * EPI_STRIDE * 4)       // 67584 B

typedef __attribute__((ext_vector_type(4))) float f32x4;
typedef __attribute__((ext_vector_type(8))) short bf16x8;

__device__ __forceinline__ ushort f2b(float f) {
  uint32_t u = __float_as_uint(f);
  uint32_t r = (u + 0x7FFFu + ((u >> 16) & 1u)) >> 16;  // RNE
  return (ushort)r;
}
__device__ __forceinline__ float b2f(ushort b) {
  return __uint_as_float(((uint32_t)b) << 16);
}

__global__ void k_cvt_bf16(const float* __restrict__ in, ushort* __restrict__ out, int n4) {
  int i = blockIdx.x * blockDim.x + threadIdx.x;
  int stride = gridDim.x * blockDim.x;
  for (; i < n4; i += stride) {
    float4 v = ((const float4*)in)[i];
    ushort4 o;
    o.x = f2b(v.x); o.y = f2b(v.y); o.z = f2b(v.z); o.w = f2b(v.w);
    ((ushort4*)out)[i] = o;
  }
}

// W (f32 [K][128]) -> bf16 pre-swizzled to GEMM LDS layout: byte = c*2K + ((2k)^((c&7)<<4))
__global__ void k_cvtW(const float* __restrict__ W, ushort* __restrict__ Wswz, int K) {
  int idx = blockIdx.x * blockDim.x + threadIdx.x;
  if (idx >= K * 128) return;
  int k = idx >> 7, c = idx & 127;
  ushort b = f2b(W[idx]);
  *(ushort*)((char*)Wswz + c * (K * 2) + ((k * 2) ^ ((c & 7) << 4))) = b;
}

// ---- bucketed CSR build ----
__global__ __launch_bounds__(256) void k_bin(const int* __restrict__ srcA, const int* __restrict__ dstA,
                                             int* __restrict__ bucket_cnt, int* __restrict__ binned) {
  __shared__ int hist[NBUCK];
  __shared__ int lscan[NBUCK];
  __shared__ int rsv[NBUCK];
  __shared__ int lpos[NBUCK];
  __shared__ int ws[4];
  __shared__ int2 ent[BIN_CHUNK];
  int t = threadIdx.x;
  int e0 = blockIdx.x * BIN_CHUNK;
  int cnt = min(BIN_CHUNK, N_EDGES - e0);
  for (int i = t; i < NBUCK; i += 256) hist[i] = 0;
  __syncthreads();
  for (int j = t; j < cnt; j += 256) atomicAdd(&hist[dstA[e0 + j] >> BUCKET_BITS], 1);
  __syncthreads();
  {
    int lane = t & 63, wv = t >> 6;
    int v = (t < NBUCK) ? hist[t] : 0;
    int inc = v;
    for (int d = 1; d < 64; d <<= 1) { int x = __shfl_up(inc, d); if (lane >= d) inc += x; }
    if (lane == 63) ws[wv] = inc;
    __syncthreads();
    int wbase = 0;
    for (int k = 0; k < wv; ++k) wbase += ws[k];
    if (t < NBUCK) {
      int excl = wbase + inc - v;
      lscan[t] = excl;
      lpos[t] = excl;
      rsv[t] = (v > 0) ? atomicAdd(&bucket_cnt[t], v) : 0;
    }
  }
  __syncthreads();
  for (int j = t; j < cnt; j += 256) {
    int s = srcA[e0 + j], d = dstA[e0 + j];
    int p = atomicAdd(&lpos[d >> BUCKET_BITS], 1);
    ent[p] = make_int2(s, d);
  }
  __syncthreads();
  for (int j = t; j < cnt; j += 256) {
    int2 E = ent[j];
    int b = E.y >> BUCKET_BITS;
    int pos = rsv[b] + (j - lscan[b]);
    if (pos < BUCK_CAP)
      binned[b * BUCK_CAP + pos] = (E.x << BUCKET_BITS) | (E.y & (BUCKET_NODES - 1));
  }
}

__global__ __launch_bounds__(256) void k_bucket_scan(const int* __restrict__ bucket_cnt,
                                                     int* __restrict__ bucket_base) {
  __shared__ int ws[4];
  int t = threadIdx.x;
  int lane = t & 63, wv = t >> 6;
  int v = (t < NBUCK) ? bucket_cnt[t] : 0;
  int inc = v;
  for (int d = 1; d < 64; d <<= 1) { int x = __shfl_up(inc, d); if (lane >= d) inc += x; }
  if (lane == 63) ws[wv] = inc;
  __syncthreads();
  int wbase = 0;
  for (int k = 0; k < wv; ++k) wbase += ws[k];
  if (t < NBUCK) bucket_base[t] = (wbase + inc - v) + t * BUCK_SLACK;
}

__global__ __launch_bounds__(512) void k_csr(const int* __restrict__ binned,
                                             const int* __restrict__ bucket_cnt,
                                             const int* __restrict__ bucket_base,
                                             int2* __restrict__ off2, int* __restrict__ srcs) {
  __shared__ int deg[BUCKET_NODES];
  __shared__ int sAb[BUCKET_NODES];
  __shared__ int sBb[BUCKET_NODES];
  __shared__ int pos[BUCKET_NODES];
  __shared__ int epk[BUCK_CAP];
  int b = blockIdx.x;
  int t = threadIdx.x;
  int cnt = min(bucket_cnt[b], BUCK_CAP);
  int gbase = bucket_base[b];
  int n0 = b * BUCKET_NODES;
  int nn = min(BUCKET_NODES, N_NODES - n0);
  deg[t] = 0;
  __syncthreads();
  for (int j = t; j < cnt; j += 512) {
    int p = binned[b * BUCK_CAP + j];
    epk[j] = p;
    atomicAdd(&deg[p & (BUCKET_NODES - 1)], 1);
  }
  __syncthreads();
  int d = deg[t];
  int dp = (d + 7) & ~7;
  int* sA = sAb; int* sB = sBb;
  sA[t] = dp;
  __syncthreads();
  for (int q = 1; q < 512; q <<= 1) {
    int x = sA[t];
    if (t >= q) x += sA[t - q];
    sB[t] = x;
    __syncthreads();
    int* tp = sA; sA = sB; sB = tp;
  }
  int ex = sA[t] - dp;
  pos[t] = ex;
  if (t < nn) off2[n0 + t] = make_int2(gbase + ex, gbase + ex + dp);
  __syncthreads();
  for (int j = t; j < cnt; j += 512) {
    int p = epk[j];
    int q = atomicAdd(&pos[p & (BUCKET_NODES - 1)], 1);
    srcs[gbase + q] = p >> BUCKET_BITS;
  }
  __syncthreads();
  for (int q = ex + d; q < ex + dp; ++q) srcs[gbase + q] = N_NODES;  // zero-row dummies
}

// segment-sum over a bf16 node table (optional relu on gathered words) -> bf16 agg table.
__global__ __launch_bounds__(256) void k_aggr(
    const ushort* __restrict__ table, const int2* __restrict__ off2, const int* __restrict__ srcs,
    ushort* __restrict__ outagg, int n, int relu)
{
  int node = blockIdx.x * 4 + (threadIdx.x >> 6);
  if (node >= n) return;
  int lane = threadIdx.x & 63;
  int2 se = off2[node];
  int s = __builtin_amdgcn_readfirstlane(se.x);
  int e = __builtin_amdgcn_readfirstlane(se.y);
  float a0 = 0.f, a1 = 0.f;
  int j = s;
  for (; j + 16 <= e; j += 16) {
    int ix[16];
#pragma unroll
    for (int q = 0; q < 16; ++q) ix[q] = srcs[j + q];
    uint32_t u[16];
#pragma unroll
    for (int q = 0; q < 16; ++q)
      u[q] = *(const uint32_t*)(table + (size_t)ix[q] * 128 + lane * 2);
#pragma unroll
    for (int q = 0; q < 16; ++q) {
      if (relu) { uint32_t m = (u[q] >> 15) & 0x00010001u; u[q] &= ~(m * 0xFFFFu); }
      a0 += __uint_as_float(u[q] << 16);
      a1 += __uint_as_float(u[q] & 0xFFFF0000u);
    }
  }
  if (j < e) {  // remainder exactly 8
    int ix[8];
#pragma unroll
    for (int q = 0; q < 8; ++q) ix[q] = srcs[j + q];
    uint32_t u[8];
#pragma unroll
    for (int q = 0; q < 8; ++q)
      u[q] = *(const uint32_t*)(table + (size_t)ix[q] * 128 + lane * 2);
#pragma unroll
    for (int q = 0; q < 8; ++q) {
      if (relu) { uint32_t m = (u[q] >> 15) & 0x00010001u; u[q] &= ~(m * 0xFFFFu); }
      a0 += __uint_as_float(u[q] << 16);
      a1 += __uint_as_float(u[q] & 0xFFFF0000u);
    }
  }
  uint32_t pk = (uint32_t)f2b(a0) | ((uint32_t)f2b(a1) << 16);
  *(uint32_t*)(outagg + (size_t)node * 128 + lane * 2) = pk;
}

// GEMM: out = A @ W + bias (+ resid); LDS-transposed coalesced epilogue.
__global__ __launch_bounds__(256) void k_gemm(
    const ushort* __restrict__ A0, const ushort* __restrict__ A1,
    const ushort* __restrict__ Wswz, const ushort* __restrict__ resid,
    const float* __restrict__ bias,
    ushort* __restrict__ outb, float* __restrict__ outf, int n, int K)
{
  extern __shared__ char smem[];
  int bytes = K * 256;
  for (int idx = threadIdx.x * 16; idx < bytes; idx += 256 * 16)
    *(uint4*)(smem + idx) = *(const uint4*)((const char*)Wswz + idx);
  __syncthreads();

  int lane = threadIdx.x & 63;
  int wv = threadIdx.x >> 6;
  int rowBase = blockIdx.x * 128 + wv * 32;
  int rl = lane & 15;
  int kh = lane >> 4;
  int r0 = rowBase + rl, r1 = r0 + 16;
  int r0c = min(r0, n - 1), r1c = min(r1, n - 1);

  f32x4 acc[2][8];
#pragma unroll
  for (int i = 0; i < 2; ++i)
#pragma unroll
    for (int j = 0; j < 8; ++j)
      acc[i][j] = (f32x4){0.f, 0.f, 0.f, 0.f};

  int nks = K >> 5;
  bf16x8 a0, a1;
  {
    int kof = (kh << 3);
    a0 = *(const bf16x8*)(A0 + (size_t)r0c * 128 + kof);
    a1 = *(const bf16x8*)(A0 + (size_t)r1c * 128 + kof);
  }
  for (int ks = 0; ks < nks; ++ks) {
    bf16x8 na0 = a0, na1 = a1;
    if (ks + 1 < nks) {
      int ksn = ks + 1;
      const ushort* Asrc = (ksn < 4) ? A0 : A1;
      int kof = ((ksn & 3) << 5) + (kh << 3);
      na0 = *(const bf16x8*)(Asrc + (size_t)r0c * 128 + kof);
      na1 = *(const bf16x8*)(Asrc + (size_t)r1c * 128 + kof);
    }
    int kk = (ks << 5) + (kh << 3);
#pragma unroll
    for (int ct = 0; ct < 8; ++ct) {
      int col = (ct << 4) + rl;
      bf16x8 b = *(const bf16x8*)(smem + col * (K * 2) + ((kk * 2) ^ ((col & 7) << 4)));
      acc[0][ct] = __builtin_amdgcn_mfma_f32_16x16x32_bf16(a0, b, acc[0][ct], 0, 0, 0);
      acc[1][ct] = __builtin_amdgcn_mfma_f32_16x16x32_bf16(a1, b, acc[1][ct], 0, 0, 0);
    }
    a0 = na0; a1 = na1;
  }

  // ---- LDS-transposed epilogue: acc -> smem f32 [128][EPI_STRIDE], then coalesced out ----
  __syncthreads();  // done reading W
  float* sm = (float*)smem;
#pragma unroll
  for (int ri = 0; ri < 2; ++ri)
#pragma unroll
    for (int ct = 0; ct < 8; ++ct) {
      int col = (ct << 4) + rl;
#pragma unroll
      for (int j = 0; j < 4; ++j) {
        int lrow = wv * 32 + ri * 16 + kh * 4 + j;
        sm[lrow * EPI_STRIDE + col] = acc[ri][ct][j];
      }
    }
  __syncthreads();

  int colb = (lane & 31) << 2;               // 4-col group, constant per thread
  int rbase = (wv << 1) + (lane >> 5);       // row within 8-row stripe
  float4 bv4 = *(const float4*)(bias + colb);
#pragma unroll
  for (int i = 0; i < 16; ++i) {
    int rowL = rbase + (i << 3);
    int grow = blockIdx.x * 128 + rowL;
    if (grow >= n) continue;
    float4 v = *(const float4*)(sm + rowL * EPI_STRIDE + colb);
    v.x += bv4.x; v.y += bv4.y; v.z += bv4.z; v.w += bv4.w;
    size_t gidx = (size_t)grow * 128 + colb;
    if (resid) {
      ushort4 rr = *(const ushort4*)(resid + gidx);
      v.x += b2f(rr.x); v.y += b2f(rr.y); v.z += b2f(rr.z); v.w += b2f(rr.w);
    }
    if (outf) {
      *(float4*)(outf + gidx) = v;
    } else {
      ushort4 o;
      o.x = f2b(v.x); o.y = f2b(v.y); o.z = f2b(v.z); o.w = f2b(v.w);
      *(ushort4*)(outb + gidx) = o;
    }
  }
}

extern "C" void kernel_launch(void* const* d_in, const int* in_sizes, int n_in,
                              void* d_out, int out_size, void* d_ws, size_t ws_size,
                              hipStream_t stream) {
  const float* x = (const float*)d_in[0];
  const int* ei  = (const int*)d_in[1];
  const int* src = ei;
  const int* dst = ei + N_EDGES;
  const float* Wp[4] = {(const float*)d_in[4], (const float*)d_in[6],
                        (const float*)d_in[8], (const float*)d_in[10]};
  const float* bp[4] = {(const float*)d_in[5], (const float*)d_in[7],
                        (const float*)d_in[9], (const float*)d_in[11]};
  const int Kl[4] = {128, 256, 256, 256};

  char* w = (char*)d_ws;
  auto alloc = [&](size_t bytes) {
    char* p = w;
    w += (bytes + 255) & ~(size_t)255;
    return p;
  };
  ushort* x_bf  = (ushort*)alloc((size_t)(N_NODES + 8) * 128 * 2);  // + zero row
  ushort* hbf   = (ushort*)alloc((size_t)(N_NODES + 8) * 128 * 2);  // + zero row
  ushort* xagg  = (ushort*)alloc((size_t)N_NODES * 128 * 2);
  ushort* ragg  = (ushort*)alloc((size_t)N_NODES * 128 * 2);
  int2*   off2  = (int2*)  alloc((size_t)N_NODES * 8);
  int*    srcs  = (int*)   alloc((size_t)SRCS_CAP * 4);
  int*    binned = (int*)  alloc((size_t)NBUCK * BUCK_CAP * 4);
  int*    bucket_cnt  = (int*)alloc((size_t)NBUCK * 4);
  int*    bucket_base = (int*)alloc((size_t)NBUCK * 4);
  ushort* Wswz[4];
  for (int l = 0; l < 4; ++l) Wswz[l] = (ushort*)alloc((size_t)Kl[l] * 128 * 2);
  if ((size_t)(w - (char*)d_ws) > ws_size) return;

  hipMemsetAsync(bucket_cnt, 0, (size_t)NBUCK * 4, stream);
  hipMemsetAsync(x_bf + (size_t)N_NODES * 128, 0, 256, stream);  // zero rows for dummies
  hipMemsetAsync(hbf + (size_t)N_NODES * 128, 0, 256, stream);
  k_cvt_bf16<<<2048, 256, 0, stream>>>(x, x_bf, N_NODES * 128 / 4);
  for (int l = 0; l < 4; ++l)
    k_cvtW<<<(Kl[l] * 128 + 255) / 256, 256, 0, stream>>>(Wp[l], Wswz[l], Kl[l]);
  k_bin<<<NB_BIN, 256, 0, stream>>>(src, dst, bucket_cnt, binned);
  k_bucket_scan<<<1, 256, 0, stream>>>(bucket_cnt, bucket_base);
  k_csr<<<NBUCK, 512, 0, stream>>>(binned, bucket_cnt, bucket_base, off2, srcs);

  int gfull = (N_NODES + 127) / 128;
  int groot = (N_ROOTS + 127) / 128;
  int afull = (N_NODES + 3) / 4;
  int aroot = (N_ROOTS + 3) / 4;
  size_t sm128 = EPI_LDS;  // max(128*256, EPI_LDS)
  size_t sm256 = EPI_LDS;  // max(256*256, EPI_LDS) = 67584

  // xagg = segment_sum(x)  (reused by all layers; replaces layer-0's gather by linearity)
  k_aggr<<<afull, 256, 0, stream>>>(x_bf, off2, srcs, xagg, N_NODES, 0);
  // h0 = xagg @ W0 + b0
  k_gemm<<<gfull, 256, sm128, stream>>>(xagg, xagg, Wswz[0], nullptr, bp[0],
                                        hbf, nullptr, N_NODES, 128);
  // layers 1-2: ragg = segment_sum(relu(h)); h += [ragg,xagg]@W + b
  for (int l = 1; l < 3; ++l) {
    k_aggr<<<afull, 256, 0, stream>>>(hbf, off2, srcs, ragg, N_NODES, 1);
    k_gemm<<<gfull, 256, sm256, stream>>>(ragg, xagg, Wswz[l], hbf, bp[l],
                                          hbf, nullptr, N_NODES, 256);
  }
  // layer 3: only roots (nodes 0..4095) are read by the output
  k_aggr<<<aroot, 256, 0, stream>>>(hbf, off2, srcs, ragg, N_ROOTS, 1);
  k_gemm<<<groot, 256, sm256, stream>>>(ragg, xagg, Wswz[3], hbf, bp[3],
                                        nullptr, (float*)d_out, N_ROOTS, 256);
}